// Round 1
// baseline (421.773 us; speedup 1.0000x reference)
//
#include <hip/hip_runtime.h>

#define B_ 4
#define H_ 16
#define SQ 1024
#define SK 1024
#define DHD 64
#define E_ 1024

typedef unsigned short ushort_t;
typedef __attribute__((ext_vector_type(8))) short short8;
typedef __attribute__((ext_vector_type(4))) float f32x4;

static __device__ __forceinline__ ushort_t f2bf(float f) {
  unsigned x = __float_as_uint(f);
  return (ushort_t)((x + 0x7fffu + ((x >> 16) & 1u)) >> 16);
}
static __device__ __forceinline__ float bf2f(ushort_t h) {
  return __uint_as_float(((unsigned)h) << 16);
}
// load 8 consecutive f32, split into hi/lo bf16 fragments (fp32 emulation)
static __device__ __forceinline__ void split8(const float* p, short8& hi, short8& lo) {
  f32x4 v0 = *(const f32x4*)p;
  f32x4 v1 = *(const f32x4*)(p + 4);
#pragma unroll
  for (int i = 0; i < 8; ++i) {
    float f = (i < 4) ? v0[i] : v1[i - 4];
    ushort_t h = f2bf(f);
    hi[i] = (short)h;
    lo[i] = (short)f2bf(f - bf2f(h));
  }
}
static __device__ __forceinline__ f32x4 mfma16(short8 a, short8 b, f32x4 c) {
  return __builtin_amdgcn_mfma_f32_16x16x32_bf16(a, b, c, 0, 0, 0);
}

// ---- V transpose: [B,H,Sk,64] f32 -> hi/lo bf16 [B,H,64,Sk] ----
__global__ __launch_bounds__(256) void vtrans_kernel(const float* __restrict__ V,
                                                     ushort_t* __restrict__ vth,
                                                     ushort_t* __restrict__ vtl) {
  __shared__ float tile[64][65];
  int bh = blockIdx.x >> 4;
  int kt = blockIdx.x & 15;   // 16 k-tiles of 64
  int tid = threadIdx.x;
  const float* src = V + ((size_t)bh * SK + (size_t)kt * 64) * DHD;
#pragma unroll
  for (int i = 0; i < 16; ++i) {
    int idx = i * 256 + tid;
    tile[idx >> 6][idx & 63] = src[idx];
  }
  __syncthreads();
#pragma unroll
  for (int i = 0; i < 16; ++i) {
    int idx = i * 256 + tid;
    int d = idx >> 6, kk = idx & 63;
    float f = tile[kk][d];
    ushort_t h = f2bf(f);
    size_t o = ((size_t)bh * DHD + d) * SK + kt * 64 + kk;
    vth[o] = h;
    vtl[o] = f2bf(f - bf2f(h));
  }
}

// ---- q projection: q = emb @ Wq^T + bq, output hi/lo bf16 [B,H,Sq,64] ----
__global__ __launch_bounds__(256) void proj_kernel(const float* __restrict__ emb,
                                                   const float* __restrict__ wq,
                                                   const float* __restrict__ bq,
                                                   ushort_t* __restrict__ qh,
                                                   ushort_t* __restrict__ ql) {
  int tid = threadIdx.x, wid = tid >> 6, lane = tid & 63;
  int lr = lane & 15, lg = lane >> 4;
  int m0 = blockIdx.y * 64 + (wid >> 1) * 32;
  int n0 = blockIdx.x * 64 + (wid & 1) * 32;
  f32x4 acc[2][2];
#pragma unroll
  for (int i = 0; i < 2; ++i)
#pragma unroll
    for (int j = 0; j < 2; ++j) acc[i][j] = (f32x4){0.f, 0.f, 0.f, 0.f};

  for (int kk = 0; kk < E_; kk += 32) {
    short8 ah[2], al[2], wh[2], wl[2];
#pragma unroll
    for (int g = 0; g < 2; ++g) {
      split8(emb + (size_t)(m0 + g * 16 + lr) * E_ + kk + lg * 8, ah[g], al[g]);
      split8(wq + (size_t)(n0 + g * 16 + lr) * E_ + kk + lg * 8, wh[g], wl[g]);
    }
#pragma unroll
    for (int i = 0; i < 2; ++i)
#pragma unroll
      for (int j = 0; j < 2; ++j) {
        acc[i][j] = mfma16(ah[i], wh[j], acc[i][j]);
        acc[i][j] = mfma16(ah[i], wl[j], acc[i][j]);
        acc[i][j] = mfma16(al[i], wh[j], acc[i][j]);
      }
  }
#pragma unroll
  for (int i = 0; i < 2; ++i)
#pragma unroll
    for (int j = 0; j < 2; ++j)
#pragma unroll
      for (int r = 0; r < 4; ++r) {
        int m = m0 + i * 16 + lg * 4 + r;       // D layout: row=(lane>>4)*4+r
        int n = n0 + j * 16 + lr;               //           col=lane&15
        float v = acc[i][j][r] + bq[n];
        int b = m >> 10, sq = m & 1023, h = n >> 6, dd = n & 63;
        size_t o = ((size_t)(b * H_ + h) * SQ + sq) * DHD + dd;
        ushort_t hh = f2bf(v);
        qh[o] = hh;
        ql[o] = f2bf(v - bf2f(hh));
      }
}

// ---- fused attention: scores -> softmax -> colmax atomic -> PV ----
__global__ __launch_bounds__(512) void attn_kernel(const ushort_t* __restrict__ qh,
                                                   const ushort_t* __restrict__ ql,
                                                   const float* __restrict__ K,
                                                   const ushort_t* __restrict__ vth,
                                                   const ushort_t* __restrict__ vtl,
                                                   const float* __restrict__ M,
                                                   const float* __restrict__ dpm,
                                                   float* __restrict__ out,
                                                   int* __restrict__ colmax) {
  __shared__ float sc[32][1028];   // 32 q-rows x 1024 k (+4 pad) fp32
  __shared__ float rowscale[32];

  // XCD-locality swizzle: confine each (b,h) to one XCD (round-robin assumption)
  int bid = blockIdx.x;
  int x = bid & 7, j = bid >> 3;
  int bh = (x << 3) | (j >> 5);
  int qb = j & 31;
  int b = bh >> 4, h = bh & 15;
  int q0 = qb << 5;

  int tid = threadIdx.x, wid = tid >> 6, lane = tid & 63;
  int lr = lane & 15, lg = lane >> 4;

  // q fragments for this tile (hi/lo), kept in registers
  short8 aqh[2][2], aql[2][2];
  {
    const ushort_t* qrh = qh + ((size_t)bh * SQ + q0) * DHD;
    const ushort_t* qrl = ql + ((size_t)bh * SQ + q0) * DHD;
#pragma unroll
    for (int qg = 0; qg < 2; ++qg)
#pragma unroll
      for (int dh = 0; dh < 2; ++dh) {
        size_t off = (size_t)(qg * 16 + lr) * DHD + dh * 32 + lg * 8;
        aqh[qg][dh] = *(const short8*)(qrh + off);
        aql[qg][dh] = *(const short8*)(qrl + off);
      }
  }

  // phase 1: S = q K^T into LDS (raw dot, scale later). wave owns 128 k-cols.
  int c0 = wid * 128;
  for (int kt = 0; kt < 8; ++kt) {
    int col = c0 + kt * 16 + lr;
    const float* krow = K + ((size_t)bh * SK + col) * DHD;
    short8 bh0, bl0, bh1, bl1;
    split8(krow + lg * 8, bh0, bl0);
    split8(krow + 32 + lg * 8, bh1, bl1);
#pragma unroll
    for (int qg = 0; qg < 2; ++qg) {
      f32x4 acc = (f32x4){0.f, 0.f, 0.f, 0.f};
      acc = mfma16(aqh[qg][0], bh0, acc);
      acc = mfma16(aqh[qg][0], bl0, acc);
      acc = mfma16(aql[qg][0], bh0, acc);
      acc = mfma16(aqh[qg][1], bh1, acc);
      acc = mfma16(aqh[qg][1], bl1, acc);
      acc = mfma16(aql[qg][1], bh1, acc);
      int cc = c0 + kt * 16 + lr;
#pragma unroll
      for (int r = 0; r < 4; ++r) sc[qg * 16 + lg * 4 + r][cc] = acc[r];
    }
  }
  __syncthreads();

  // phase 2: stream M once, exact softmax per row (wave handles 4 rows)
  for (int rr = 0; rr < 4; ++rr) {
    int r = wid * 4 + rr;
    const float* mr = M + ((size_t)bh * SQ + q0 + r) * SK;
    float sv[16];
    float mx = -3.0e38f;
#pragma unroll
    for (int i = 0; i < 16; ++i) {
      int c = i * 64 + lane;
      float s = sc[r][c] * 0.125f - mr[c];
      sv[i] = s;
      mx = fmaxf(mx, s);
    }
#pragma unroll
    for (int mm = 1; mm < 64; mm <<= 1) mx = fmaxf(mx, __shfl_xor(mx, mm));
    float ls = 0.f;
#pragma unroll
    for (int i = 0; i < 16; ++i) {
      float p = __expf(sv[i] - mx);
      sc[r][i * 64 + lane] = p;
      ls += p;
    }
#pragma unroll
    for (int mm = 1; mm < 64; mm <<= 1) ls += __shfl_xor(ls, mm);
    if (lane == 0) rowscale[r] = dpm[b * SQ + q0 + r] / ls;
  }
  __syncthreads();

  // column max over this q-tile -> device-scope atomicMax (floats >= 0)
  for (int c = tid; c < SK; c += 512) {
    float cm = 0.f;
#pragma unroll 8
    for (int r = 0; r < 32; ++r) cm = fmaxf(cm, sc[r][c] * rowscale[r]);
    atomicMax(colmax + (size_t)bh * SK + c, __float_as_int(cm));
  }

  // PV: each wave owns one 16(q) x 16(d) output tile
  int qg = wid >> 2, dg = wid & 3;
  f32x4 acc = (f32x4){0.f, 0.f, 0.f, 0.f};
  for (int ks = 0; ks < SK; ks += 32) {
    short8 ph, pl;
    split8(&sc[qg * 16 + lr][ks + lg * 8], ph, pl);
    size_t vo = ((size_t)bh * DHD + dg * 16 + lr) * SK + ks + lg * 8;
    short8 vh = *(const short8*)(vth + vo);
    short8 vl = *(const short8*)(vtl + vo);
    acc = mfma16(ph, vh, acc);
    acc = mfma16(ph, vl, acc);
    acc = mfma16(pl, vh, acc);
  }
#pragma unroll
  for (int r = 0; r < 4; ++r) {
    int rt = qg * 16 + lg * 4 + r;
    out[((size_t)b * SQ + q0 + rt) * E_ + h * DHD + dg * 16 + lr] = acc[r] * rowscale[rt];
  }
}

// ---- target_score = sum over heads of colmax ----
__global__ __launch_bounds__(256) void tscore_kernel(const int* __restrict__ colmax,
                                                     float* __restrict__ out) {
  int g = blockIdx.x * 256 + threadIdx.x;  // B*Sk = 4096
  int b = g >> 10, k = g & 1023;
  float s = 0.f;
#pragma unroll
  for (int hh = 0; hh < H_; ++hh) s += __int_as_float(colmax[((b * H_ + hh) << 10) + k]);
  out[(size_t)B_ * SQ * E_ + g] = s;
}

extern "C" void kernel_launch(void* const* d_in, const int* in_sizes, int n_in,
                              void* d_out, int out_size, void* d_ws, size_t ws_size,
                              hipStream_t stream) {
  const float* dp_emb = (const float*)d_in[0];
  const float* dp_mask = (const float*)d_in[1];
  const float* K = (const float*)d_in[2];
  const float* V = (const float*)d_in[3];
  const float* M = (const float*)d_in[4];
  const float* Wq = (const float*)d_in[5];
  const float* bq = (const float*)d_in[6];
  float* out = (float*)d_out;

  char* ws = (char*)d_ws;
  ushort_t* qh = (ushort_t*)(ws);                          // 8 MB
  ushort_t* ql = (ushort_t*)(ws + (8ull << 20));           // 8 MB
  ushort_t* vth = (ushort_t*)(ws + (16ull << 20));         // 8 MB
  ushort_t* vtl = (ushort_t*)(ws + (24ull << 20));         // 8 MB
  int* colmax = (int*)(ws + (32ull << 20));                // 256 KB

  hipMemsetAsync(colmax, 0, (size_t)B_ * H_ * SK * sizeof(int), stream);
  vtrans_kernel<<<B_ * H_ * 16, 256, 0, stream>>>(V, vth, vtl);
  proj_kernel<<<dim3(E_ / 64, (B_ * SQ) / 64), 256, 0, stream>>>(dp_emb, Wq, bq, qh, ql);
  attn_kernel<<<B_ * H_ * (SQ / 32), 512, 0, stream>>>(qh, ql, K, vth, vtl, M, dp_mask, out,
                                                       colmax);
  tscore_kernel<<<(B_ * SK) / 256, 256, 0, stream>>>(colmax, out);
}

// Round 2
// 239.173 us; speedup vs baseline: 1.7635x; 1.7635x over previous
//
#include <hip/hip_runtime.h>

#define B_ 4
#define H_ 16
#define SQ 1024
#define SK 1024
#define DHD 64
#define E_ 1024

typedef _Float16 half_t;
typedef __attribute__((ext_vector_type(8))) _Float16 half8;
typedef __attribute__((ext_vector_type(4))) float f32x4;

static __device__ __forceinline__ f32x4 mfma16h(half8 a, half8 b, f32x4 c) {
  return __builtin_amdgcn_mfma_f32_16x16x32_f16(a, b, c, 0, 0, 0);
}

// ---- fp32 -> fp16 elementwise (8 elems/thread) ----
__global__ __launch_bounds__(256) void cvt_kernel(const float* __restrict__ src,
                                                  half_t* __restrict__ dst, int n8) {
  int i = blockIdx.x * 256 + threadIdx.x;
  if (i >= n8) return;
  f32x4 v0 = *(const f32x4*)(src + (size_t)i * 8);
  f32x4 v1 = *(const f32x4*)(src + (size_t)i * 8 + 4);
  half8 h;
#pragma unroll
  for (int j = 0; j < 4; ++j) {
    h[j] = (half_t)v0[j];
    h[4 + j] = (half_t)v1[j];
  }
  *(half8*)(dst + (size_t)i * 8) = h;
}

// ---- V transpose: [BH,Sk,64] f32 -> fp16 [BH,64,Sk] ----
__global__ __launch_bounds__(256) void vtrans_kernel(const float* __restrict__ V,
                                                     half_t* __restrict__ vt) {
  __shared__ float tile[64][65];
  int bh = blockIdx.x >> 4;
  int kt = blockIdx.x & 15;
  int tid = threadIdx.x;
  const float* src = V + ((size_t)bh * SK + (size_t)kt * 64) * DHD;
#pragma unroll
  for (int i = 0; i < 16; ++i) {
    int idx = i * 256 + tid;
    tile[idx >> 6][idx & 63] = src[idx];
  }
  __syncthreads();
#pragma unroll
  for (int i = 0; i < 16; ++i) {
    int idx = i * 256 + tid;
    int d = idx >> 6, kk = idx & 63;
    vt[((size_t)bh * DHD + d) * SK + kt * 64 + kk] = (half_t)tile[kk][d];
  }
}

// ---- q projection: fp16 GEMM, q = (emb @ Wq^T + bq) * 0.125, out [BH,Sq,64] fp16 ----
__global__ __launch_bounds__(256) void proj_kernel(const half_t* __restrict__ emb,
                                                   const half_t* __restrict__ wq,
                                                   const float* __restrict__ bq,
                                                   half_t* __restrict__ qh) {
  int tid = threadIdx.x, wid = tid >> 6, lane = tid & 63;
  int lr = lane & 15, lg = lane >> 4;
  int m0 = blockIdx.y * 64 + (wid >> 1) * 32;
  int n0 = blockIdx.x * 64 + (wid & 1) * 32;
  f32x4 acc[2][2];
#pragma unroll
  for (int i = 0; i < 2; ++i)
#pragma unroll
    for (int j = 0; j < 2; ++j) acc[i][j] = (f32x4){0.f, 0.f, 0.f, 0.f};

  for (int kk = 0; kk < E_; kk += 32) {
    half8 a[2], b[2];
#pragma unroll
    for (int g = 0; g < 2; ++g) {
      a[g] = *(const half8*)(emb + (size_t)(m0 + g * 16 + lr) * E_ + kk + lg * 8);
      b[g] = *(const half8*)(wq + (size_t)(n0 + g * 16 + lr) * E_ + kk + lg * 8);
    }
#pragma unroll
    for (int i = 0; i < 2; ++i)
#pragma unroll
      for (int j = 0; j < 2; ++j) acc[i][j] = mfma16h(a[i], b[j], acc[i][j]);
  }
#pragma unroll
  for (int i = 0; i < 2; ++i)
#pragma unroll
    for (int j = 0; j < 2; ++j)
#pragma unroll
      for (int r = 0; r < 4; ++r) {
        int m = m0 + i * 16 + lg * 4 + r;  // row=(lane>>4)*4+r
        int n = n0 + j * 16 + lr;          // col=lane&15
        float v = (acc[i][j][r] + bq[n]) * 0.125f;
        int b = m >> 10, sq = m & 1023, h = n >> 6, dd = n & 63;
        qh[((size_t)(b * H_ + h) * SQ + sq) * DHD + dd] = (half_t)v;
      }
}

// ---- fused attention: QK^T(+M fused) -> in-reg softmax -> fp16 panel -> colmax -> PV ----
__global__ __launch_bounds__(512, 4) void attn_kernel(const half_t* __restrict__ qh,
                                                      const half_t* __restrict__ kh,
                                                      const half_t* __restrict__ vt,
                                                      const float* __restrict__ M,
                                                      const float* __restrict__ dpm,
                                                      float* __restrict__ out,
                                                      int* __restrict__ colmax) {
  __shared__ half_t panel[32][1032];  // probs (raw exp), fp16, padded stride
  __shared__ float wred[8][32];
  __shared__ float gmaxs[32];
  __shared__ float rowscale[32];

  // XCD-locality swizzle: confine each bh to one XCD
  int bid = blockIdx.x;
  int x = bid & 7, j = bid >> 3;   // 2048 blocks: 8 XCD x 256
  int bh = (x << 3) | (j >> 5);    // 8 bh per XCD
  int q0 = (j & 31) << 5;          // 32 q-tiles of 32 rows
  int b = bh >> 4, h = bh & 15;

  int tid = threadIdx.x, wid = tid >> 6, lane = tid & 63;
  int lr = lane & 15, lg = lane >> 4;
  int c0 = wid * 128;  // this wave's 128 k-columns

  // q A-fragments: rows q0+qg*16+lr, d = dh*32+lg*8
  half8 aq[2][2];
#pragma unroll
  for (int qg = 0; qg < 2; ++qg)
#pragma unroll
    for (int dh = 0; dh < 2; ++dh)
      aq[qg][dh] = *(const half8*)(qh + ((size_t)bh * SQ + q0 + qg * 16 + lr) * DHD +
                                   dh * 32 + lg * 8);

  // M row pointers for this lane (col base c0+lr)
  const float* mp[2][4];
#pragma unroll
  for (int qg = 0; qg < 2; ++qg)
#pragma unroll
    for (int r = 0; r < 4; ++r)
      mp[qg][r] = M + ((size_t)bh * SQ + q0 + qg * 16 + lg * 4 + r) * SK + c0 + lr;

  // phase 1: S = q.K^T - M, kept in registers (64 f32/lane)
  f32x4 S[2][8];
#pragma unroll
  for (int kt = 0; kt < 8; ++kt) {
    int col = c0 + kt * 16 + lr;
    const half_t* kr = kh + ((size_t)bh * SK + col) * DHD;
    half8 b0 = *(const half8*)(kr + lg * 8);
    half8 b1 = *(const half8*)(kr + 32 + lg * 8);
#pragma unroll
    for (int qg = 0; qg < 2; ++qg) {
      f32x4 acc = (f32x4){0.f, 0.f, 0.f, 0.f};
      acc = mfma16h(aq[qg][0], b0, acc);
      acc = mfma16h(aq[qg][1], b1, acc);
      f32x4 mv;
#pragma unroll
      for (int r = 0; r < 4; ++r) mv[r] = mp[qg][r][kt * 16];
      S[qg][kt] = acc - mv;  // 0.125 scale folded into q at proj
    }
  }

  // phase 2a: row max (in-reg + shfl within 16-lane group + LDS cross-wave)
  float mx[2][4];
#pragma unroll
  for (int qg = 0; qg < 2; ++qg)
#pragma unroll
    for (int r = 0; r < 4; ++r) {
      float m0 = S[qg][0][r];
#pragma unroll
      for (int kt = 1; kt < 8; ++kt) m0 = fmaxf(m0, S[qg][kt][r]);
#pragma unroll
      for (int off = 1; off < 16; off <<= 1) m0 = fmaxf(m0, __shfl_xor(m0, off));
      mx[qg][r] = m0;
    }
  if (lr == 0) {
#pragma unroll
    for (int qg = 0; qg < 2; ++qg)
#pragma unroll
      for (int r = 0; r < 4; ++r) wred[wid][qg * 16 + lg * 4 + r] = mx[qg][r];
  }
  __syncthreads();
  if (tid < 32) {
    float g = wred[0][tid];
#pragma unroll
    for (int w = 1; w < 8; ++w) g = fmaxf(g, wred[w][tid]);
    gmaxs[tid] = g;
  }
  __syncthreads();

  // phase 2b: p = exp(S - gmax), write fp16 panel, partial row sums
  float g[2][4];
#pragma unroll
  for (int qg = 0; qg < 2; ++qg)
#pragma unroll
    for (int r = 0; r < 4; ++r) g[qg][r] = gmaxs[qg * 16 + lg * 4 + r];
  float sm[2][4] = {{0.f, 0.f, 0.f, 0.f}, {0.f, 0.f, 0.f, 0.f}};
#pragma unroll
  for (int qg = 0; qg < 2; ++qg)
#pragma unroll
    for (int kt = 0; kt < 8; ++kt)
#pragma unroll
      for (int r = 0; r < 4; ++r) {
        float p = __expf(S[qg][kt][r] - g[qg][r]);
        panel[qg * 16 + lg * 4 + r][c0 + kt * 16 + lr] = (half_t)p;
        sm[qg][r] += p;
      }
#pragma unroll
  for (int qg = 0; qg < 2; ++qg)
#pragma unroll
    for (int r = 0; r < 4; ++r) {
#pragma unroll
      for (int off = 1; off < 16; off <<= 1) sm[qg][r] += __shfl_xor(sm[qg][r], off);
    }
  if (lr == 0) {
#pragma unroll
    for (int qg = 0; qg < 2; ++qg)
#pragma unroll
      for (int r = 0; r < 4; ++r) wred[wid][qg * 16 + lg * 4 + r] = sm[qg][r];
  }
  __syncthreads();
  if (tid < 32) {
    float ls = 0.f;
#pragma unroll
    for (int w = 0; w < 8; ++w) ls += wred[w][tid];
    rowscale[tid] = dpm[b * SQ + q0 + tid] / ls;
  }
  __syncthreads();

  // colmax -> device atomicMax (values >= 0, float-as-int monotone)
  for (int c = tid; c < SK; c += 512) {
    float cm = 0.f;
#pragma unroll 8
    for (int r = 0; r < 32; ++r) cm = fmaxf(cm, (float)panel[r][c] * rowscale[r]);
    atomicMax(colmax + (size_t)bh * SK + c, __float_as_int(cm));
  }

  // PV: 8 waves = 2(q) x 4(d) tiles of 16x16, full k per wave
  int qgw = wid >> 2, dg = wid & 3;
  const half_t* vrow = vt + ((size_t)bh * DHD + dg * 16 + lr) * SK;
  f32x4 acc = (f32x4){0.f, 0.f, 0.f, 0.f};
  for (int ks = 0; ks < SK; ks += 32) {
    half8 pa = *(const half8*)&panel[qgw * 16 + lr][ks + lg * 8];
    half8 vb = *(const half8*)(vrow + ks + lg * 8);
    acc = mfma16h(pa, vb, acc);
  }
#pragma unroll
  for (int r = 0; r < 4; ++r) {
    int rt = qgw * 16 + lg * 4 + r;
    out[((size_t)b * SQ + q0 + rt) * E_ + h * DHD + dg * 16 + lr] = acc[r] * rowscale[rt];
  }
}

// ---- target_score = sum over heads of colmax ----
__global__ __launch_bounds__(256) void tscore_kernel(const int* __restrict__ colmax,
                                                     float* __restrict__ out) {
  int g = blockIdx.x * 256 + threadIdx.x;  // B*Sk = 4096
  int b = g >> 10, k = g & 1023;
  float s = 0.f;
#pragma unroll
  for (int hh = 0; hh < H_; ++hh) s += __int_as_float(colmax[((b * H_ + hh) << 10) + k]);
  out[(size_t)B_ * SQ * E_ + g] = s;
}

extern "C" void kernel_launch(void* const* d_in, const int* in_sizes, int n_in,
                              void* d_out, int out_size, void* d_ws, size_t ws_size,
                              hipStream_t stream) {
  const float* dp_emb = (const float*)d_in[0];
  const float* dp_mask = (const float*)d_in[1];
  const float* K = (const float*)d_in[2];
  const float* V = (const float*)d_in[3];
  const float* M = (const float*)d_in[4];
  const float* Wq = (const float*)d_in[5];
  const float* bq = (const float*)d_in[6];
  float* out = (float*)d_out;

  char* ws = (char*)d_ws;
  half_t* q_h = (half_t*)(ws);                       // 8 MB  [BH,Sq,64]
  half_t* k_h = (half_t*)(ws + (8ull << 20));        // 8 MB  [BH,Sk,64]
  half_t* vt_h = (half_t*)(ws + (16ull << 20));      // 8 MB  [BH,64,Sk]
  half_t* emb_h = (half_t*)(ws + (24ull << 20));     // 8 MB  [B*Sq,E]
  half_t* wq_h = (half_t*)(ws + (33ull << 20));      // 2 MB  [E,E]
  int* colmax = (int*)(ws + (36ull << 20));          // 256 KB

  hipMemsetAsync(colmax, 0, (size_t)B_ * H_ * SK * sizeof(int), stream);
  cvt_kernel<<<(B_ * SQ * E_ / 8 + 255) / 256, 256, 0, stream>>>(dp_emb, emb_h, B_ * SQ * E_ / 8);
  cvt_kernel<<<(E_ * E_ / 8 + 255) / 256, 256, 0, stream>>>(Wq, wq_h, E_ * E_ / 8);
  cvt_kernel<<<(B_ * H_ * SK * DHD / 8 + 255) / 256, 256, 0, stream>>>(K, k_h,
                                                                       B_ * H_ * SK * DHD / 8);
  vtrans_kernel<<<B_ * H_ * 16, 256, 0, stream>>>(V, vt_h);
  proj_kernel<<<dim3(E_ / 64, (B_ * SQ) / 64), 256, 0, stream>>>(emb_h, wq_h, bq, q_h);
  attn_kernel<<<B_ * H_ * (SQ / 32), 512, 0, stream>>>(q_h, k_h, vt_h, M, dp_mask, out, colmax);
  tscore_kernel<<<(B_ * SK) / 256, 256, 0, stream>>>(colmax, out);
}